// Round 7
// baseline (502.972 us; speedup 1.0000x reference)
//
#include <hip/hip_runtime.h>
#include <hip/hip_bf16.h>

#define BB 8
#define CC 64
#define NN 4096
#define KK 20
#define OO 64
#define FMAXV 3.402823466e38f

typedef __attribute__((ext_vector_type(8))) short short8;   // 8 bf16 = 4 VGPRs (MFMA A/B frag)
typedef __attribute__((ext_vector_type(4))) float f32x4;    // MFMA C/D frag

// ---------------------------------------------------------------------------
// Kernel PREP: transpose x (B,C,N)->xt/xb (B,N,C), sq[n], and u/v GEMV fused.
// u[b,n,o] = dot(W2[o],x_n); v[b,n,o] = dot(W1[o]-W2[o],x_n) + bias[o]
// ---------------------------------------------------------------------------
__global__ __launch_bounds__(256) void kprep(const float* __restrict__ x,
                                             const float* __restrict__ W,
                                             const float* __restrict__ bias,
                                             float* __restrict__ xt,
                                             unsigned short* __restrict__ xb,
                                             float* __restrict__ sq,
                                             float* __restrict__ u,
                                             float* __restrict__ v) {
  __shared__ float tile[64][65];       // [c][n]
  const int b = blockIdx.y, n0 = blockIdx.x * 64;
  const int lane = threadIdx.x & 63, grp = threadIdx.x >> 6;
  #pragma unroll
  for (int j = 0; j < 16; ++j) {
    int c = grp + j * 4;
    tile[c][lane] = x[((size_t)b * CC + c) * NN + n0 + lane];
  }
  // weight load overlaps the x loads (o = lane)
  float w2r[64], wdr[64];
  const float4* W4 = (const float4*)W;
  #pragma unroll
  for (int c4 = 0; c4 < 16; ++c4) {
    float4 q1 = W4[lane * 32 + c4];       // W1 part
    float4 q2 = W4[lane * 32 + 16 + c4];  // W2 part
    w2r[c4*4]=q2.x; w2r[c4*4+1]=q2.y; w2r[c4*4+2]=q2.z; w2r[c4*4+3]=q2.w;
    wdr[c4*4]=q1.x-q2.x; wdr[c4*4+1]=q1.y-q2.y; wdr[c4*4+2]=q1.z-q2.z; wdr[c4*4+3]=q1.w-q2.w;
  }
  const float bo = bias[lane];
  __syncthreads();
  #pragma unroll
  for (int j = 0; j < 16; ++j) {
    int n = grp + j * 4;
    float vv = tile[lane][n];
    size_t off = ((size_t)b * NN + n0 + n) * CC + lane;
    xt[off] = vv;
    unsigned int uu = __builtin_bit_cast(unsigned int, vv);
    xb[off] = (unsigned short)((uu + 0x7FFFu + ((uu >> 16) & 1u)) >> 16);  // RNE bf16
  }
  if (threadIdx.x < 64) {
    float s = 0.f;
    #pragma unroll
    for (int c = 0; c < 64; ++c) { float vv = tile[c][lane]; s += vv * vv; }
    sq[(size_t)b * NN + n0 + lane] = s;
  }
  for (int j = 0; j < 16; ++j) {
    int nl = grp * 16 + j;
    float du = 0.f, dv = 0.f;
    #pragma unroll
    for (int c = 0; c < 64; ++c) {
      float xv = tile[c][nl];             // broadcast read
      du += w2r[c] * xv;
      dv += wdr[c] * xv;
    }
    size_t off = ((size_t)b * NN + n0 + nl) * OO + lane;
    u[off] = du;
    v[off] = dv + bo;
  }
}

// ---------------------------------------------------------------------------
// helpers
// ---------------------------------------------------------------------------
__device__ __forceinline__ int lanes_below(unsigned long long m) {
  unsigned lo = (unsigned)m, hi = (unsigned)(m >> 32);
  int c = __builtin_amdgcn_mbcnt_lo(lo, 0);
  return (int)__builtin_amdgcn_mbcnt_hi(hi, (unsigned)c);
}

// monotone float->uint, truncate to 20 bits, pack 12-bit global col idx
__device__ __forceinline__ unsigned packkey(float d, int m) {
  unsigned u = __builtin_bit_cast(unsigned, d);
  u ^= ((int)u < 0) ? 0xFFFFFFFFu : 0x80000000u;
  return (u & 0xFFFFF000u) | (unsigned)m;
}

// loose inverse: float threshold >= every d whose packkey < t (superset filter)
__device__ __forceinline__ float unpackkey(unsigned t) {
  unsigned u = t | 0xFFFu;
  u = (u & 0x80000000u) ? (u ^ 0x80000000u) : ~u;
  return __builtin_bit_cast(float, u);
}

// full 64-element bitonic sort (ascending), 1 element per lane, 21 stages
__device__ __forceinline__ unsigned bitonic64(unsigned v, int lane) {
  #pragma unroll
  for (int k = 2; k <= 64; k <<= 1) {
    #pragma unroll
    for (int j = k >> 1; j >= 1; j >>= 1) {
      unsigned o = (unsigned)__shfl_xor((int)v, j);
      bool up    = ((lane & k) == 0);
      bool lower = ((lane & j) == 0);
      unsigned mn = (v < o) ? v : o;
      unsigned mx = (v < o) ? o : v;
      v = (up == lower) ? mn : mx;
    }
  }
  return v;
}

// ---------------------------------------------------------------------------
// Kernel KNN7: barrier-free; 8 ROWS per wave (A-frag rows duplicated into
// lanes 8-15; quads 2-3 masked out of selection) x 2048 cols. 8192 waves ->
// 8 blocks/CU, LDS 12 KB -> grid-delivered full residency. Top-32/row via
// ring + bitonic64. Output: kcand[b][half][row][32] sorted packed keys.
// ---------------------------------------------------------------------------
__global__ __launch_bounds__(256, 4) void kknn7(const unsigned short* __restrict__ xb,
                                                const float* __restrict__ sq,
                                                unsigned* __restrict__ kcand) {
  __shared__ unsigned slist[4][8][32];   // 4 KB
  __shared__ unsigned sbuf[4][8][64];    // 8 KB (outstanding <= 47)
  const int lane = threadIdx.x & 63, w = threadIdx.x >> 6;
  const int wid = blockIdx.x * 4 + w;            // 0..8191
  const int b = wid >> 10;
  const int half = (wid >> 9) & 1;
  const int n0g = (wid & 511) * 8;               // global row base (8 rows)
  const int ch0 = half * (NN / 2);               // global col base
  const int l15 = lane & 15, q = lane >> 4;
  const bool qlo = (q < 2);
  const unsigned long long qmask = 0xFFFFull << (q * 16);

  const unsigned short* xbB = xb + (size_t)b * NN * CC;
  const float* sqB = sq + (size_t)b * NN;

  #pragma unroll
  for (int i = 0; i < 4; ++i) {
    int idx = i * 64 + lane;
    slist[w][idx >> 5][idx & 31] = 0xFFFFFFFFu;
  }

  // A frags: row = n0g + (l15 & 7)  (lanes 8-15 duplicate rows 0-7)
  short8 afr[2];
  #pragma unroll
  for (int ks = 0; ks < 2; ++ks)
    afr[ks] = __builtin_bit_cast(short8,
        *(const int4*)(xbB + (size_t)(n0g + (l15 & 7)) * CC + ks * 32 + q * 8));

  // per-lane state: slot j tracks row q*4+j (valid for q<2)
  float tauf4[4];
  int cnt4[4], done4[4];
  #pragma unroll
  for (int j = 0; j < 4; ++j) { tauf4[j] = FMAXV; cnt4[j] = 0; done4[j] = 0; }

  for (int t = 0; t < 32; ++t) {
    const int cb = ch0 + t * 64;
    short8 bfr[4][2];
    float sv[4];
    #pragma unroll
    for (int ct = 0; ct < 4; ++ct) {
      #pragma unroll
      for (int ks = 0; ks < 2; ++ks)
        bfr[ct][ks] = __builtin_bit_cast(short8,
            *(const int4*)(xbB + (size_t)(cb + ct * 16 + l15) * CC + ks * 32 + q * 8));
      sv[ct] = sqB[cb + ct * 16 + l15];
    }
    f32x4 acc[4];
    #pragma unroll
    for (int ct = 0; ct < 4; ++ct) {
      acc[ct] = (f32x4){0.f, 0.f, 0.f, 0.f};
      acc[ct] = __builtin_amdgcn_mfma_f32_16x16x32_bf16(afr[0], bfr[ct][0], acc[ct], 0, 0, 0);
      acc[ct] = __builtin_amdgcn_mfma_f32_16x16x32_bf16(afr[1], bfr[ct][1], acc[ct], 0, 0, 0);
    }

    #pragma unroll
    for (int ct = 0; ct < 4; ++ct) {
      const int colg = cb + ct * 16 + l15;
      float dj[4];
      bool pj[4];
      #pragma unroll
      for (int j = 0; j < 4; ++j) {
        float d = sv[ct] - 2.f * acc[ct][j];
        if (colg == n0g + ((q * 4 + j) & 7)) d = FMAXV;   // exclude self
        dj[j] = d;
        pj[j] = qlo && (d <= tauf4[j]);
      }
      if (!__ballot(pj[0] | pj[1] | pj[2] | pj[3])) continue;  // fast path
      #pragma unroll
      for (int j = 0; j < 4; ++j) {
        unsigned long long bal = __ballot(pj[j]);
        if (!bal) continue;
        const int rowl = q * 4 + j;                 // 0..7 for passing quads
        int posq = lanes_below(bal & qmask);
        if (pj[j]) sbuf[w][rowl][(cnt4[j] + posq) & 63] = packkey(dj[j], colg);
        cnt4[j] += __popcll(bal & qmask);           // q>=2 adds 0
        unsigned long long mb = __ballot(cnt4[j] - done4[j] >= 32);
        while (mb) {
          int src = __ffsll(mb) - 1;
          int qm = src >> 4;                        // 0 or 1
          int rowm = qm * 4 + j;
          int dsrc = __shfl(done4[j], src);
          unsigned v = (lane < 32) ? slist[w][rowm][lane]
                                   : sbuf[w][rowm][(dsrc + lane - 32) & 63];
          v = bitonic64(v, lane);
          if (lane < 32) slist[w][rowm][lane] = v;
          unsigned tn = (unsigned)__shfl((int)v, 31);
          if (q == qm) { tauf4[j] = unpackkey(tn); done4[j] += 32; }
          mb &= ~(0xFFFFull << (qm * 16));
        }
      }
    }
  }

  // flush leftovers (< 32 outstanding per row)
  #pragma unroll
  for (int j = 0; j < 4; ++j) {
    unsigned long long mb = __ballot(cnt4[j] > done4[j]);
    while (mb) {
      int src = __ffsll(mb) - 1;
      int qm = src >> 4;
      int rowm = qm * 4 + j;
      int dsrc = __shfl(done4[j], src);
      int csrc = __shfl(cnt4[j], src);
      int rem = csrc - dsrc;
      unsigned v = (lane < 32) ? slist[w][rowm][lane]
                 : ((lane - 32) < rem ? sbuf[w][rowm][(dsrc + lane - 32) & 63] : 0xFFFFFFFFu);
      v = bitonic64(v, lane);
      if (lane < 32) slist[w][rowm][lane] = v;
      if (q == qm) done4[j] = cnt4[j];
      mb &= ~(0xFFFFull << (qm * 16));
    }
  }

  // write out sorted top-32 per row (coalesced): 8 rows x 32
  unsigned* kc = kcand + (((size_t)b * 2 + half) * NN + n0g) * 32;
  #pragma unroll
  for (int i = 0; i < 4; ++i) {
    int idx = i * 64 + lane;
    kc[idx] = slist[w][idx >> 5][idx & 31];
  }
}

// ---------------------------------------------------------------------------
// Kernel POST: per row-pair, union the two half top-32 lists -> exact f32
// refine -> sorted top-20; then directly gather u for stats (S1/S2 per
// channel into replicated gS) and umax/umin. knn never hits global memory.
// ---------------------------------------------------------------------------
__global__ __launch_bounds__(256) void kpost(const unsigned* __restrict__ kcand,
                                             const float* __restrict__ xt,
                                             const float* __restrict__ sq,
                                             const float* __restrict__ u,
                                             const float* __restrict__ v,
                                             float* __restrict__ umax,
                                             float* __restrict__ umin,
                                             float* __restrict__ gS) {
  const int lane = threadIdx.x & 63, w = threadIdx.x >> 6;
  const int gw = blockIdx.x * 4 + w;
  const int hl = lane & 31;
  float s1 = 0.f, s2 = 0.f;

  for (int it = 0; it < 2; ++it) {
    const int rbase = gw * 4 + it * 2;          // global row index (b*N+n), even
    const int b = rbase >> 12;
    const int n = rbase & (NN - 1);

    const unsigned* kc0 = kcand + (((size_t)b * 2 + 0) * NN) * 32;
    const unsigned* kc1 = kcand + (((size_t)b * 2 + 1) * NN) * 32;
    unsigned vA = (lane < 32) ? kc0[(size_t)n * 32 + lane] : kc1[(size_t)n * 32 + (lane - 32)];
    vA = bitonic64(vA, lane);
    unsigned vB = (lane < 32) ? kc0[(size_t)(n + 1) * 32 + lane] : kc1[(size_t)(n + 1) * 32 + (lane - 32)];
    vB = bitonic64(vB, lane);
    unsigned kx = (unsigned)__shfl_xor((int)vB, 32);
    unsigned key = (lane < 32) ? vA : kx;       // lanes 0-31: row n; 32-63: row n+1
    int m = (int)(key & 0xFFFu);
    const int rowg = n + ((lane >= 32) ? 1 : 0);

    // exact f32 key
    const float* xtB = xt + (size_t)b * NN * CC;
    const float* sqB = sq + (size_t)b * NN;
    const float4* pr = (const float4*)(xtB + (size_t)rowg * CC);
    const float4* pm = (const float4*)(xtB + (size_t)m * CC);
    float t0 = 0.f, t1 = 0.f, t2 = 0.f, t3 = 0.f;
    #pragma unroll
    for (int i = 0; i < 16; ++i) {
      float4 a = pr[i], c = pm[i];
      t0 += a.x * c.x; t1 += a.y * c.y; t2 += a.z * c.z; t3 += a.w * c.w;
    }
    float ev = sqB[m] - 2.f * ((t0 + t1) + (t2 + t3));

    // bitonic sort 32 (ev, m) pairs ascending within each 32-lane half
    #pragma unroll
    for (int k = 2; k <= 32; k <<= 1) {
      #pragma unroll
      for (int jj = k >> 1; jj >= 1; jj >>= 1) {
        float e2 = __shfl_xor(ev, jj);
        int   m2 = __shfl_xor(m, jj);
        bool up    = ((hl & k) == 0);
        bool lower = ((hl & jj) == 0);
        bool less  = (e2 < ev) || (e2 == ev && m2 < m);
        bool take  = (up == lower) ? less : !less;
        if (take) { ev = e2; m = m2; }
      }
    }
    // lane hl holds rank-hl neighbor index for its half's row

    // stats gather: lane = channel; rows n, n+1
    const float* uB = u + (size_t)b * NN * OO;
    #pragma unroll
    for (int rr = 0; rr < 2; ++rr) {
      const int rown = n + rr;
      float vv = v[((size_t)b * NN + rown) * OO + lane];
      float mx = -FMAXV, mn = FMAXV;
      #pragma unroll
      for (int k = 0; k < KK; ++k) {
        int id = __shfl(m, rr * 32 + k);
        float uu = uB[(size_t)id * OO + lane];
        float y = vv + uu;
        s1 += y; s2 += y * y;
        mx = fmaxf(mx, uu); mn = fminf(mn, uu);
      }
      umax[((size_t)b * NN + rown) * OO + lane] = mx;
      umin[((size_t)b * NN + rown) * OO + lane] = mn;
    }
  }

  __shared__ float r1[4][64], r2[4][64];
  r1[w][lane] = s1; r2[w][lane] = s2;
  __syncthreads();
  if (w == 0) {
    float a = r1[0][lane] + r1[1][lane] + r1[2][lane] + r1[3][lane];
    float c = r2[0][lane] + r2[1][lane] + r2[2][lane] + r2[3][lane];
    float* g = gS + (blockIdx.x & 7) * 128;     // 8 replicas vs atomic serialization
    atomicAdd(&g[lane], a);
    atomicAdd(&g[64 + lane], c);
  }
}

// ---------------------------------------------------------------------------
// Kernel O: normalize, affine, relu, max over k (via umax/umin), transposed store
// ---------------------------------------------------------------------------
__global__ __launch_bounds__(256) void kout(const float* __restrict__ v,
                                            const float* __restrict__ umax,
                                            const float* __restrict__ umin,
                                            const float* __restrict__ gS,
                                            const float* __restrict__ gamma,
                                            const float* __restrict__ beta,
                                            float* __restrict__ out) {
  __shared__ float sA[64], sB[64];
  __shared__ float zt[64][65];
  const int b = blockIdx.y, n0 = blockIdx.x * 64;
  const int lane = threadIdx.x & 63, w = threadIdx.x >> 6;
  if (threadIdx.x < 64) {
    float s1 = 0.f, s2 = 0.f;
    #pragma unroll
    for (int rsub = 0; rsub < 8; ++rsub) {
      s1 += gS[rsub * 128 + lane];
      s2 += gS[rsub * 128 + 64 + lane];
    }
    const float cnt = (float)BB * NN * KK;
    float m  = s1 / cnt;
    float var = s2 / cnt - m * m;
    float A = gamma[lane] * rsqrtf(var + 1e-5f);
    sA[lane] = A;
    sB[lane] = beta[lane] - A * m;
  }
  __syncthreads();
  for (int j = 0; j < 16; ++j) {
    int nl = w * 16 + j;
    size_t off = ((size_t)b * NN + n0 + nl) * OO + lane;
    float A = sA[lane];
    float c0 = A * v[off] + sB[lane];
    float z = c0 + A * ((A > 0.f) ? umax[off] : umin[off]);
    zt[nl][lane] = fmaxf(z, 0.f);
  }
  __syncthreads();
  for (int j = 0; j < 16; ++j) {
    int o = w * 16 + j;
    out[((size_t)b * OO + o) * NN + n0 + lane] = zt[lane][o];
  }
}

// ---------------------------------------------------------------------------
extern "C" void kernel_launch(void* const* d_in, const int* in_sizes, int n_in,
                              void* d_out, int out_size, void* d_ws, size_t ws_size,
                              hipStream_t stream) {
  const float* x     = (const float*)d_in[0];
  const float* W     = (const float*)d_in[1];
  const float* bias  = (const float*)d_in[2];
  const float* gamma = (const float*)d_in[3];
  const float* beta  = (const float*)d_in[4];
  float* out = (float*)d_out;

  float* xt  = (float*)d_ws;                    // 2,097,152 f
  float* sq  = xt  + (size_t)BB*NN*CC;          //    32,768 f
  float* u   = sq  + (size_t)BB*NN;             // 2,097,152 f
  float* v   = u   + (size_t)BB*NN*OO;          // 2,097,152 f
  float* umx = v   + (size_t)BB*NN*OO;          // 2,097,152 f
  float* umn = umx + (size_t)BB*NN*OO;          // 2,097,152 f
  float* gS  = umn + (size_t)BB*NN*OO;          //     1,024 f (8 replicas)
  unsigned short* xb = (unsigned short*)(gS + 1024);          // 2,097,152 bf16
  unsigned* kcand = (unsigned*)(xb + (size_t)BB*NN*CC);       // 2,097,152 u32

  hipMemsetAsync(gS, 0, 1024 * sizeof(float), stream);
  kprep<<<dim3(NN/64, BB), 256, 0, stream>>>(x, W, bias, xt, xb, sq, u, v);
  kknn7<<<dim3(2048),      256, 0, stream>>>(xb, sq, kcand);
  kpost<<<dim3(2048),      256, 0, stream>>>(kcand, xt, sq, u, v, umx, umn, gS);
  kout <<<dim3(NN/64, BB), 256, 0, stream>>>(v, umx, umn, gS, gamma, beta, out);
}

// Round 11
// 417.039 us; speedup vs baseline: 1.2061x; 1.2061x over previous
//
#include <hip/hip_runtime.h>
#include <hip/hip_bf16.h>

#define BB 8
#define CC 64
#define NN 4096
#define KK 20
#define OO 64
#define FMAXV 3.402823466e38f

typedef __attribute__((ext_vector_type(8))) short short8;   // 8 bf16 = 4 VGPRs (MFMA A/B frag)
typedef __attribute__((ext_vector_type(4))) float f32x4;    // MFMA C/D frag

// ---------------------------------------------------------------------------
// Kernel PREP (verified r7): transpose x (B,C,N)->xt/xb (B,N,C), sq, u/v GEMV.
// ---------------------------------------------------------------------------
__global__ __launch_bounds__(256) void kprep(const float* __restrict__ x,
                                             const float* __restrict__ W,
                                             const float* __restrict__ bias,
                                             float* __restrict__ xt,
                                             unsigned short* __restrict__ xb,
                                             float* __restrict__ sq,
                                             float* __restrict__ u,
                                             float* __restrict__ v) {
  __shared__ float tile[64][65];       // [c][n]
  const int b = blockIdx.y, n0 = blockIdx.x * 64;
  const int lane = threadIdx.x & 63, grp = threadIdx.x >> 6;
  #pragma unroll
  for (int j = 0; j < 16; ++j) {
    int c = grp + j * 4;
    tile[c][lane] = x[((size_t)b * CC + c) * NN + n0 + lane];
  }
  float w2r[64], wdr[64];
  const float4* W4 = (const float4*)W;
  #pragma unroll
  for (int c4 = 0; c4 < 16; ++c4) {
    float4 q1 = W4[lane * 32 + c4];       // W1 part
    float4 q2 = W4[lane * 32 + 16 + c4];  // W2 part
    w2r[c4*4]=q2.x; w2r[c4*4+1]=q2.y; w2r[c4*4+2]=q2.z; w2r[c4*4+3]=q2.w;
    wdr[c4*4]=q1.x-q2.x; wdr[c4*4+1]=q1.y-q2.y; wdr[c4*4+2]=q1.z-q2.z; wdr[c4*4+3]=q1.w-q2.w;
  }
  const float bo = bias[lane];
  __syncthreads();
  #pragma unroll
  for (int j = 0; j < 16; ++j) {
    int n = grp + j * 4;
    float vv = tile[lane][n];
    size_t off = ((size_t)b * NN + n0 + n) * CC + lane;
    xt[off] = vv;
    unsigned int uu = __builtin_bit_cast(unsigned int, vv);
    xb[off] = (unsigned short)((uu + 0x7FFFu + ((uu >> 16) & 1u)) >> 16);  // RNE bf16
  }
  if (threadIdx.x < 64) {
    float s = 0.f;
    #pragma unroll
    for (int c = 0; c < 64; ++c) { float vv = tile[c][lane]; s += vv * vv; }
    sq[(size_t)b * NN + n0 + lane] = s;
  }
  for (int j = 0; j < 16; ++j) {
    int nl = grp * 16 + j;
    float du = 0.f, dv = 0.f;
    #pragma unroll
    for (int c = 0; c < 64; ++c) {
      float xv = tile[c][nl];             // broadcast read
      du += w2r[c] * xv;
      dv += wdr[c] * xv;
    }
    size_t off = ((size_t)b * NN + n0 + nl) * OO + lane;
    u[off] = du;
    v[off] = dv + bo;
  }
}

// ---------------------------------------------------------------------------
// helpers (verified rounds 3-7)
// ---------------------------------------------------------------------------
__device__ __forceinline__ int lanes_below(unsigned long long m) {
  unsigned lo = (unsigned)m, hi = (unsigned)(m >> 32);
  int c = __builtin_amdgcn_mbcnt_lo(lo, 0);
  return (int)__builtin_amdgcn_mbcnt_hi(hi, (unsigned)c);
}

// monotone float->uint, truncate to 20 bits, pack 12-bit global col idx
__device__ __forceinline__ unsigned packkey(float d, int m) {
  unsigned u = __builtin_bit_cast(unsigned, d);
  u ^= ((int)u < 0) ? 0xFFFFFFFFu : 0x80000000u;
  return (u & 0xFFFFF000u) | (unsigned)m;
}

// loose inverse: float threshold >= every d whose packkey < t (superset filter)
__device__ __forceinline__ float unpackkey(unsigned t) {
  unsigned u = t | 0xFFFu;
  u = (u & 0x80000000u) ? (u ^ 0x80000000u) : ~u;
  return __builtin_bit_cast(float, u);
}

// full 64-element bitonic sort (ascending), 1 element per lane, 21 stages
__device__ __forceinline__ unsigned bitonic64(unsigned v, int lane) {
  #pragma unroll
  for (int k = 2; k <= 64; k <<= 1) {
    #pragma unroll
    for (int j = k >> 1; j >= 1; j >>= 1) {
      unsigned o = (unsigned)__shfl_xor((int)v, j);
      bool up    = ((lane & k) == 0);
      bool lower = ((lane & j) == 0);
      unsigned mn = (v < o) ? v : o;
      unsigned mx = (v < o) ? o : v;
      v = (up == lower) ? mn : mx;
    }
  }
  return v;
}

// ---------------------------------------------------------------------------
// Kernel KNN6 (byte-identical to round-6 VERIFIED kernel): barrier-free;
// 256-thr blocks of 4 independent waves; each wave 16 rows x 2048 cols (half
// the col range). Top-32/row via ring + bitonic64 merge.
// Output: kcand[b][half][row][32] sorted packed keys.
// ---------------------------------------------------------------------------
__global__ __launch_bounds__(256, 4) void kknn6(const unsigned short* __restrict__ xb,
                                                const float* __restrict__ sq,
                                                unsigned* __restrict__ kcand) {
  __shared__ unsigned slist[4][16][32];   // 8 KB: per-wave per-row sorted top-32
  __shared__ unsigned sbuf[4][16][64];    // 16 KB: per-wave per-row ring (outstanding <= 47)
  const int lane = threadIdx.x & 63, w = threadIdx.x >> 6;
  const int wid = blockIdx.x * 4 + w;            // 0..4095
  const int b = wid >> 9;
  const int half = (wid >> 8) & 1;
  const int n0g = (wid & 255) * 16;              // global row base
  const int ch0 = half * (NN / 2);               // global col base
  const int l15 = lane & 15, q = lane >> 4;
  const unsigned long long qmask = 0xFFFFull << (q * 16);

  const unsigned short* xbB = xb + (size_t)b * NN * CC;
  const float* sqB = sq + (size_t)b * NN;

  // init slist sentinels (per wave)
  #pragma unroll
  for (int i = 0; i < 8; ++i) {
    int idx = i * 64 + lane;
    slist[w][idx >> 5][idx & 31] = 0xFFFFFFFFu;
  }

  // A frags: rows n0g + l15, k = ks*32 + q*8
  short8 afr[2];
  #pragma unroll
  for (int ks = 0; ks < 2; ++ks)
    afr[ks] = __builtin_bit_cast(short8, *(const int4*)(xbB + (size_t)(n0g + l15) * CC + ks * 32 + q * 8));

  // per-lane state: slot j tracks row q*4+j
  float tauf4[4];
  int cnt4[4], done4[4];
  #pragma unroll
  for (int j = 0; j < 4; ++j) { tauf4[j] = FMAXV; cnt4[j] = 0; done4[j] = 0; }

  for (int t = 0; t < 32; ++t) {
    const int cb = ch0 + t * 64;
    short8 bfr[4][2];
    float sv[4];
    #pragma unroll
    for (int ct = 0; ct < 4; ++ct) {
      #pragma unroll
      for (int ks = 0; ks < 2; ++ks)
        bfr[ct][ks] = __builtin_bit_cast(short8,
            *(const int4*)(xbB + (size_t)(cb + ct * 16 + l15) * CC + ks * 32 + q * 8));
      sv[ct] = sqB[cb + ct * 16 + l15];
    }
    f32x4 acc[4];
    #pragma unroll
    for (int ct = 0; ct < 4; ++ct) {
      acc[ct] = (f32x4){0.f, 0.f, 0.f, 0.f};
      acc[ct] = __builtin_amdgcn_mfma_f32_16x16x32_bf16(afr[0], bfr[ct][0], acc[ct], 0, 0, 0);
      acc[ct] = __builtin_amdgcn_mfma_f32_16x16x32_bf16(afr[1], bfr[ct][1], acc[ct], 0, 0, 0);
    }

    #pragma unroll
    for (int ct = 0; ct < 4; ++ct) {
      const int colg = cb + ct * 16 + l15;
      float dj[4];
      bool pj[4];
      #pragma unroll
      for (int j = 0; j < 4; ++j) {
        float d = sv[ct] - 2.f * acc[ct][j];
        if (colg == n0g + q * 4 + j) d = FMAXV;    // exclude self
        dj[j] = d;
        pj[j] = d <= tauf4[j];
      }
      if (!__ballot(pj[0] | pj[1] | pj[2] | pj[3])) continue;  // fast path
      #pragma unroll
      for (int j = 0; j < 4; ++j) {
        unsigned long long bal = __ballot(pj[j]);
        if (!bal) continue;
        const int rowl = q * 4 + j;
        int posq = lanes_below(bal & qmask);       // rank within quad
        if (pj[j]) sbuf[w][rowl][(cnt4[j] + posq) & 63] = packkey(dj[j], colg);
        cnt4[j] += __popcll(bal & qmask);
        unsigned long long mb = __ballot(cnt4[j] - done4[j] >= 32);
        while (mb) {
          int src = __ffsll(mb) - 1;
          int qm = src >> 4;
          int rowm = qm * 4 + j;
          int dsrc = __shfl(done4[j], src);
          unsigned v = (lane < 32) ? slist[w][rowm][lane]
                                   : sbuf[w][rowm][(dsrc + lane - 32) & 63];
          v = bitonic64(v, lane);
          if (lane < 32) slist[w][rowm][lane] = v;
          unsigned tn = (unsigned)__shfl((int)v, 31);
          if (q == qm) { tauf4[j] = unpackkey(tn); done4[j] += 32; }
          mb &= ~(0xFFFFull << (qm * 16));
        }
      }
    }
  }

  // flush leftovers (< 32 outstanding per row)
  #pragma unroll
  for (int j = 0; j < 4; ++j) {
    unsigned long long mb = __ballot(cnt4[j] > done4[j]);
    while (mb) {
      int src = __ffsll(mb) - 1;
      int qm = src >> 4;
      int rowm = qm * 4 + j;
      int dsrc = __shfl(done4[j], src);
      int csrc = __shfl(cnt4[j], src);
      int rem = csrc - dsrc;
      unsigned v = (lane < 32) ? slist[w][rowm][lane]
                 : ((lane - 32) < rem ? sbuf[w][rowm][(dsrc + lane - 32) & 63] : 0xFFFFFFFFu);
      v = bitonic64(v, lane);
      if (lane < 32) slist[w][rowm][lane] = v;
      if (q == qm) done4[j] = cnt4[j];
      mb &= ~(0xFFFFull << (qm * 16));
    }
  }

  // write out sorted top-32 per row (coalesced)
  unsigned* kc = kcand + (((size_t)b * 2 + half) * NN + n0g) * 32;
  #pragma unroll
  for (int i = 0; i < 8; ++i) {
    int idx = i * 64 + lane;
    kc[idx] = slist[w][idx >> 5][idx & 31];
  }
}

// ---------------------------------------------------------------------------
// Kernel POST (verified r7): per row-pair, union the two half top-32 lists ->
// exact f32 refine (xt) -> sorted top-20; gather u for stats into replicated
// gS; umax/umin. Neighbor indices never round-trip through global.
// ---------------------------------------------------------------------------
__global__ __launch_bounds__(256) void kpost(const unsigned* __restrict__ kcand,
                                             const float* __restrict__ xt,
                                             const float* __restrict__ sq,
                                             const float* __restrict__ u,
                                             const float* __restrict__ v,
                                             float* __restrict__ umax,
                                             float* __restrict__ umin,
                                             float* __restrict__ gS) {
  const int lane = threadIdx.x & 63, w = threadIdx.x >> 6;
  const int gw = blockIdx.x * 4 + w;
  const int hl = lane & 31;
  float s1 = 0.f, s2 = 0.f;

  for (int it = 0; it < 2; ++it) {
    const int rbase = gw * 4 + it * 2;          // global row index (b*N+n), even
    const int b = rbase >> 12;
    const int n = rbase & (NN - 1);

    const unsigned* kc0 = kcand + (((size_t)b * 2 + 0) * NN) * 32;
    const unsigned* kc1 = kcand + (((size_t)b * 2 + 1) * NN) * 32;
    unsigned vA = (lane < 32) ? kc0[(size_t)n * 32 + lane] : kc1[(size_t)n * 32 + (lane - 32)];
    vA = bitonic64(vA, lane);
    unsigned vB = (lane < 32) ? kc0[(size_t)(n + 1) * 32 + lane] : kc1[(size_t)(n + 1) * 32 + (lane - 32)];
    vB = bitonic64(vB, lane);
    unsigned kx = (unsigned)__shfl_xor((int)vB, 32);
    unsigned key = (lane < 32) ? vA : kx;       // lanes 0-31: row n; 32-63: row n+1
    int m = (int)(key & 0xFFFu);
    const int rowg = n + ((lane >= 32) ? 1 : 0);

    // exact f32 key
    const float* xtB = xt + (size_t)b * NN * CC;
    const float* sqB = sq + (size_t)b * NN;
    const float4* pr = (const float4*)(xtB + (size_t)rowg * CC);
    const float4* pm = (const float4*)(xtB + (size_t)m * CC);
    float t0 = 0.f, t1 = 0.f, t2 = 0.f, t3 = 0.f;
    #pragma unroll
    for (int i = 0; i < 16; ++i) {
      float4 a = pr[i], c = pm[i];
      t0 += a.x * c.x; t1 += a.y * c.y; t2 += a.z * c.z; t3 += a.w * c.w;
    }
    float ev = sqB[m] - 2.f * ((t0 + t1) + (t2 + t3));

    // bitonic sort 32 (ev, m) pairs ascending within each 32-lane half
    #pragma unroll
    for (int k = 2; k <= 32; k <<= 1) {
      #pragma unroll
      for (int jj = k >> 1; jj >= 1; jj >>= 1) {
        float e2 = __shfl_xor(ev, jj);
        int   m2 = __shfl_xor(m, jj);
        bool up    = ((hl & k) == 0);
        bool lower = ((hl & jj) == 0);
        bool less  = (e2 < ev) || (e2 == ev && m2 < m);
        bool take  = (up == lower) ? less : !less;
        if (take) { ev = e2; m = m2; }
      }
    }

    // stats gather: lane = channel; rows n, n+1
    const float* uB = u + (size_t)b * NN * OO;
    #pragma unroll
    for (int rr = 0; rr < 2; ++rr) {
      const int rown = n + rr;
      float vv = v[((size_t)b * NN + rown) * OO + lane];
      float mx = -FMAXV, mn = FMAXV;
      #pragma unroll
      for (int k = 0; k < KK; ++k) {
        int id = __shfl(m, rr * 32 + k);
        float uu = uB[(size_t)id * OO + lane];
        float y = vv + uu;
        s1 += y; s2 += y * y;
        mx = fmaxf(mx, uu); mn = fminf(mn, uu);
      }
      umax[((size_t)b * NN + rown) * OO + lane] = mx;
      umin[((size_t)b * NN + rown) * OO + lane] = mn;
    }
  }

  __shared__ float r1[4][64], r2[4][64];
  r1[w][lane] = s1; r2[w][lane] = s2;
  __syncthreads();
  if (w == 0) {
    float a = r1[0][lane] + r1[1][lane] + r1[2][lane] + r1[3][lane];
    float c = r2[0][lane] + r2[1][lane] + r2[2][lane] + r2[3][lane];
    float* g = gS + (blockIdx.x & 7) * 128;     // 8 replicas vs atomic serialization
    atomicAdd(&g[lane], a);
    atomicAdd(&g[64 + lane], c);
  }
}

// ---------------------------------------------------------------------------
// Kernel O (verified r7): normalize, affine, relu, max over k, transposed store
// ---------------------------------------------------------------------------
__global__ __launch_bounds__(256) void kout(const float* __restrict__ v,
                                            const float* __restrict__ umax,
                                            const float* __restrict__ umin,
                                            const float* __restrict__ gS,
                                            const float* __restrict__ gamma,
                                            const float* __restrict__ beta,
                                            float* __restrict__ out) {
  __shared__ float sA[64], sB[64];
  __shared__ float zt[64][65];
  const int b = blockIdx.y, n0 = blockIdx.x * 64;
  const int lane = threadIdx.x & 63, w = threadIdx.x >> 6;
  if (threadIdx.x < 64) {
    float s1 = 0.f, s2 = 0.f;
    #pragma unroll
    for (int rsub = 0; rsub < 8; ++rsub) {
      s1 += gS[rsub * 128 + lane];
      s2 += gS[rsub * 128 + 64 + lane];
    }
    const float cnt = (float)BB * NN * KK;
    float m  = s1 / cnt;
    float var = s2 / cnt - m * m;
    float A = gamma[lane] * rsqrtf(var + 1e-5f);
    sA[lane] = A;
    sB[lane] = beta[lane] - A * m;
  }
  __syncthreads();
  for (int j = 0; j < 16; ++j) {
    int nl = w * 16 + j;
    size_t off = ((size_t)b * NN + n0 + nl) * OO + lane;
    float A = sA[lane];
    float c0 = A * v[off] + sB[lane];
    float z = c0 + A * ((A > 0.f) ? umax[off] : umin[off]);
    zt[nl][lane] = fmaxf(z, 0.f);
  }
  __syncthreads();
  for (int j = 0; j < 16; ++j) {
    int o = w * 16 + j;
    out[((size_t)b * OO + o) * NN + n0 + lane] = zt[lane][o];
  }
}

// ---------------------------------------------------------------------------
extern "C" void kernel_launch(void* const* d_in, const int* in_sizes, int n_in,
                              void* d_out, int out_size, void* d_ws, size_t ws_size,
                              hipStream_t stream) {
  const float* x     = (const float*)d_in[0];
  const float* W     = (const float*)d_in[1];
  const float* bias  = (const float*)d_in[2];
  const float* gamma = (const float*)d_in[3];
  const float* beta  = (const float*)d_in[4];
  float* out = (float*)d_out;

  float* xt  = (float*)d_ws;                    // 2,097,152 f
  float* sq  = xt  + (size_t)BB*NN*CC;          //    32,768 f
  float* u   = sq  + (size_t)BB*NN;             // 2,097,152 f
  float* v   = u   + (size_t)BB*NN*OO;          // 2,097,152 f
  float* umx = v   + (size_t)BB*NN*OO;          // 2,097,152 f
  float* umn = umx + (size_t)BB*NN*OO;          // 2,097,152 f
  float* gS  = umn + (size_t)BB*NN*OO;          //     1,024 f (8 replicas)
  unsigned short* xb = (unsigned short*)(gS + 1024);          // 2,097,152 bf16
  unsigned* kcand = (unsigned*)(xb + (size_t)BB*NN*CC);       // 2,097,152 u32 (8 MB)

  hipMemsetAsync(gS, 0, 1024 * sizeof(float), stream);
  kprep<<<dim3(NN/64, BB), 256, 0, stream>>>(x, W, bias, xt, xb, sq, u, v);
  kknn6<<<dim3(1024),      256, 0, stream>>>(xb, sq, kcand);
  kpost<<<dim3(2048),      256, 0, stream>>>(kcand, xt, sq, u, v, umx, umn, gS);
  kout <<<dim3(NN/64, BB), 256, 0, stream>>>(v, umx, umn, gS, gamma, beta, out);
}